// Round 8
// baseline (293.938 us; speedup 1.0000x reference)
//
#include <hip/hip_runtime.h>
#include <hip/hip_fp16.h>
#include <math.h>

#define NN   50000
#define EE   800000
#define HH   4
#define CC   32
#define DINN 128
#define ED   16
#define NEGS 0.2f
#define LNEPS 1e-5f
#define SCAN_NB ((NN + 255) / 256)   // 196
#define CPAD 32                      // cnt stride: 1 counter per 128B line

struct __align__(16) Hp4 { __half2 a, b, c, d; };

// ---------------------------------------------------------------------------
// K2: h = x @ W_lin (N x 128) -> hbuf fp16, plus a_src/a_dst.
// ---------------------------------------------------------------------------
__global__ __launch_bounds__(256, 3) void k_node(
        const float* __restrict__ x, const float* __restrict__ W_lin,
        const float* __restrict__ att_src, const float* __restrict__ att_dst,
        __half* __restrict__ hb, float* __restrict__ a_src, float* __restrict__ a_dst) {
    __shared__ float xr[64 * 132];      // 33.8 KB
    int t = threadIdx.x;
    int row0 = blockIdx.x * 64;

    #pragma unroll
    for (int i = 0; i < 8; ++i) {
        int idx = t + 256 * i;          // 0..2047
        int r = idx >> 5, kq = idx & 31;
        int row = row0 + r;
        float4 v = make_float4(0.f, 0.f, 0.f, 0.f);
        if (row < NN) v = ((const float4*)x)[(long)row * 32 + kq];
        *(float4*)&xr[r * 132 + kq * 4] = v;
    }
    __syncthreads();

    int colg = t & 15, rowg = t >> 4;
    int c0 = colg * 8;
    const float* Wp = W_lin + c0;
    float acc[4][8] = {};

    #pragma unroll 2
    for (int k = 0; k < DINN; k += 2) {
        float4 wa0 = *(const float4*)&Wp[(long)k * DINN];
        float4 wb0 = *(const float4*)&Wp[(long)k * DINN + 4];
        float4 wa1 = *(const float4*)&Wp[(long)(k + 1) * DINN];
        float4 wb1 = *(const float4*)&Wp[(long)(k + 1) * DINN + 4];
        #pragma unroll
        for (int i = 0; i < 4; ++i) {
            float2 xv = *(const float2*)&xr[(rowg * 4 + i) * 132 + k];
            acc[i][0] = fmaf(xv.x, wa0.x, acc[i][0]);
            acc[i][1] = fmaf(xv.x, wa0.y, acc[i][1]);
            acc[i][2] = fmaf(xv.x, wa0.z, acc[i][2]);
            acc[i][3] = fmaf(xv.x, wa0.w, acc[i][3]);
            acc[i][4] = fmaf(xv.x, wb0.x, acc[i][4]);
            acc[i][5] = fmaf(xv.x, wb0.y, acc[i][5]);
            acc[i][6] = fmaf(xv.x, wb0.z, acc[i][6]);
            acc[i][7] = fmaf(xv.x, wb0.w, acc[i][7]);
            acc[i][0] = fmaf(xv.y, wa1.x, acc[i][0]);
            acc[i][1] = fmaf(xv.y, wa1.y, acc[i][1]);
            acc[i][2] = fmaf(xv.y, wa1.z, acc[i][2]);
            acc[i][3] = fmaf(xv.y, wa1.w, acc[i][3]);
            acc[i][4] = fmaf(xv.y, wb1.x, acc[i][4]);
            acc[i][5] = fmaf(xv.y, wb1.y, acc[i][5]);
            acc[i][6] = fmaf(xv.y, wb1.z, acc[i][6]);
            acc[i][7] = fmaf(xv.y, wb1.w, acc[i][7]);
        }
    }

    int head = colg >> 2;
    int cw = c0 & 31;
    float4 as0 = *(const float4*)&att_src[head * CC + cw];
    float4 as1 = *(const float4*)&att_src[head * CC + cw + 4];
    float4 ad0 = *(const float4*)&att_dst[head * CC + cw];
    float4 ad1 = *(const float4*)&att_dst[head * CC + cw + 4];
    #pragma unroll
    for (int i = 0; i < 4; ++i) {
        int row = row0 + rowg * 4 + i;
        if (row < NN) {
            Hp4 p;
            p.a = __floats2half2_rn(acc[i][0], acc[i][1]);
            p.b = __floats2half2_rn(acc[i][2], acc[i][3]);
            p.c = __floats2half2_rn(acc[i][4], acc[i][5]);
            p.d = __floats2half2_rn(acc[i][6], acc[i][7]);
            *(Hp4*)&hb[(long)row * DINN + c0] = p;
        }
        float ps = acc[i][0]*as0.x + acc[i][1]*as0.y + acc[i][2]*as0.z + acc[i][3]*as0.w
                 + acc[i][4]*as1.x + acc[i][5]*as1.y + acc[i][6]*as1.z + acc[i][7]*as1.w;
        float pd = acc[i][0]*ad0.x + acc[i][1]*ad0.y + acc[i][2]*ad0.z + acc[i][3]*ad0.w
                 + acc[i][4]*ad1.x + acc[i][5]*ad1.y + acc[i][6]*ad1.z + acc[i][7]*ad1.w;
        ps += __shfl_xor(ps, 1); ps += __shfl_xor(ps, 2);
        pd += __shfl_xor(pd, 1); pd += __shfl_xor(pd, 2);
        if ((colg & 3) == 0 && row < NN) {
            a_src[row * 4 + head] = ps;
            a_dst[row * 4 + head] = pd;
        }
    }
}

// ---------------------------------------------------------------------------
// K3 (edgeA): 2 edges/thread. Per edge: ea GEMM, a_e, alpha logits,
// payload[e] = {half2(exp(alpha_h), a_e_h)}x4 (coalesced), and
// rank[e] = atomicAdd(cnt + dst*CPAD, 1)  (one counter per 128B line).
// ---------------------------------------------------------------------------
__global__ __launch_bounds__(256) void k_edgeA(
        const int* __restrict__ ei, const float* __restrict__ edge_attr,
        const float* __restrict__ W_ep, const float* __restrict__ b_ep,
        const float* __restrict__ W_edge, const float* __restrict__ att_edge,
        const float* __restrict__ a_src, const float* __restrict__ a_dst,
        int* __restrict__ cnt, int* __restrict__ rank,
        uint4* __restrict__ payload) {
    __shared__ float Wl[ED * ED];
    __shared__ float bl[ED];
    __shared__ float vl[ED * 4];
    int t = threadIdx.x;
    if (t < ED * ED) Wl[t] = W_ep[t];
    if (t < ED) bl[t] = b_ep[t];
    if (t >= 192 && t < 192 + 64) {      // 64 threads build v_edge
        int q = t - 192;
        int d = q >> 2, h = q & 3;
        float s = 0.f;
        #pragma unroll 8
        for (int c = 0; c < CC; ++c)
            s += W_edge[d * (HH * CC) + h * CC + c] * att_edge[h * CC + c];
        vl[q] = s;
    }
    __syncthreads();

    int e0 = blockIdx.x * 512 + t;       // edges e0 and e0+256

    #pragma unroll
    for (int u = 0; u < 2; ++u) {
        int e = e0 + u * 256;
        if (e >= EE) break;

        int src = ei[e];
        int dst = ei[EE + e];

        float a[ED];
        const float4* ap = (const float4*)(edge_attr + (long)e * ED);
        float4 a0 = ap[0], a1 = ap[1], a2 = ap[2], a3 = ap[3];
        a[0]=a0.x; a[1]=a0.y; a[2]=a0.z; a[3]=a0.w;
        a[4]=a1.x; a[5]=a1.y; a[6]=a1.z; a[7]=a1.w;
        a[8]=a2.x; a[9]=a2.y; a[10]=a2.z; a[11]=a2.w;
        a[12]=a3.x; a[13]=a3.y; a[14]=a3.z; a[15]=a3.w;

        float4 s4 = *(const float4*)&a_src[src * 4];
        float4 d4 = *(const float4*)&a_dst[dst * 4];

        // kick the atomic off early so its latency overlaps the GEMM
        int rk = atomicAdd(cnt + (long)dst * CPAD, 1);

        float r[ED];
        #pragma unroll
        for (int j = 0; j < ED; ++j) r[j] = bl[j];
        #pragma unroll
        for (int d = 0; d < ED; ++d) {
            float av = a[d];
            #pragma unroll
            for (int j = 0; j < ED; ++j) r[j] = fmaf(av, Wl[d * ED + j], r[j]);
        }

        float ae0 = 0.f, ae1 = 0.f, ae2 = 0.f, ae3 = 0.f;
        #pragma unroll
        for (int d = 0; d < ED; ++d) {
            float rd = fmaxf(r[d], 0.f);
            ae0 = fmaf(rd, vl[d * 4 + 0], ae0);
            ae1 = fmaf(rd, vl[d * 4 + 1], ae1);
            ae2 = fmaf(rd, vl[d * 4 + 2], ae2);
            ae3 = fmaf(rd, vl[d * 4 + 3], ae3);
        }

        float v0 = s4.x + d4.x + ae0;
        float v1 = s4.y + d4.y + ae1;
        float v2 = s4.z + d4.z + ae2;
        float v3 = s4.w + d4.w + ae3;
        v0 = (v0 >= 0.f) ? v0 : NEGS * v0;
        v1 = (v1 >= 0.f) ? v1 : NEGS * v1;
        v2 = (v2 >= 0.f) ? v2 : NEGS * v2;
        v3 = (v3 >= 0.f) ? v3 : NEGS * v3;

        __half2 p0 = __floats2half2_rn(__expf(v0), ae0);
        __half2 p1 = __floats2half2_rn(__expf(v1), ae1);
        __half2 p2 = __floats2half2_rn(__expf(v2), ae2);
        __half2 p3 = __floats2half2_rn(__expf(v3), ae3);
        payload[e] = make_uint4(*(unsigned*)&p0, *(unsigned*)&p1,
                                *(unsigned*)&p2, *(unsigned*)&p3);
        rank[e] = rk;
    }
}

// ---------------------------------------------------------------------------
// K4a/b/c: hierarchical exclusive scan of cnt (stride CPAD) -> row_start
// ---------------------------------------------------------------------------
__global__ __launch_bounds__(256) void k_scanA(const int* __restrict__ cnt,
                                               int* __restrict__ partial) {
    int t = threadIdx.x, b = blockIdx.x;
    int i = b * 256 + t;
    int v = (i < NN) ? cnt[(long)i * CPAD] : 0;
    #pragma unroll
    for (int d = 1; d < 64; d <<= 1) v += __shfl_xor(v, d);
    __shared__ int wt[4];
    if ((t & 63) == 0) wt[t >> 6] = v;
    __syncthreads();
    if (t == 0) partial[b] = wt[0] + wt[1] + wt[2] + wt[3];
}

__global__ __launch_bounds__(256) void k_scanB(const int* __restrict__ partial,
                                               int* __restrict__ poff,
                                               int* __restrict__ row_start) {
    int t = threadIdx.x;
    int lane = t & 63, w = t >> 6;
    int v = (t < SCAN_NB) ? partial[t] : 0;
    int sv = v;
    #pragma unroll
    for (int d = 1; d < 64; d <<= 1) {
        int o = __shfl_up(sv, d);
        if (lane >= d) sv += o;
    }
    __shared__ int wt[4];
    if (lane == 63) wt[w] = sv;
    __syncthreads();
    int base = 0;
    for (int j = 0; j < w; ++j) base += wt[j];
    if (t < SCAN_NB) poff[t] = base + sv - v;
    if (t == 255) row_start[NN] = wt[0] + wt[1] + wt[2] + wt[3];
}

__global__ __launch_bounds__(256) void k_scanC(const int* __restrict__ cnt,
                                               const int* __restrict__ poff,
                                               int* __restrict__ row_start) {
    int t = threadIdx.x, b = blockIdx.x;
    int i = b * 256 + t;
    int v = (i < NN) ? cnt[(long)i * CPAD] : 0;
    int lane = t & 63, w = t >> 6;
    int sv = v;
    #pragma unroll
    for (int d = 1; d < 64; d <<= 1) {
        int o = __shfl_up(sv, d);
        if (lane >= d) sv += o;
    }
    __shared__ int wt[4];
    if (lane == 63) wt[w] = sv;
    __syncthreads();
    int base = 0;
    for (int j = 0; j < w; ++j) base += wt[j];
    if (i < NN) row_start[i] = poff[b] + base + sv - v;
}

// ---------------------------------------------------------------------------
// K5 (edgeB): permute edge IDs into CSR order. 4 edges/thread; per edge:
// one row_start gather + ONE 4B scatter (csr_eid[q] = e).
// ---------------------------------------------------------------------------
__global__ __launch_bounds__(256) void k_edgeB(
        const int* __restrict__ ei, const int* __restrict__ rank,
        const int* __restrict__ row_start, int* __restrict__ csr_eid) {
    int base = (blockIdx.x * 256 + threadIdx.x) * 4;
    if (base + 3 < EE) {
        int4 d4 = *(const int4*)(ei + EE + base);
        int4 r4 = *(const int4*)(rank + base);
        csr_eid[row_start[d4.x] + r4.x] = base;
        csr_eid[row_start[d4.y] + r4.y] = base + 1;
        csr_eid[row_start[d4.z] + r4.z] = base + 2;
        csr_eid[row_start[d4.w] + r4.w] = base + 3;
    } else {
        for (int e = base; e < EE; ++e)
            csr_eid[row_start[ei[EE + e]] + rank[e]] = e;
    }
}

// ---------------------------------------------------------------------------
// K6: one wave per node, single pass, 8-wide unrolled, eid indirection.
// Lane owns channels {2*lane, 2*lane+1}; head = lane>>4.
// ---------------------------------------------------------------------------
__global__ __launch_bounds__(256) void k_aggregate(
        const float* __restrict__ x, const __half2* __restrict__ hb,
        const float* __restrict__ a_src, const float* __restrict__ a_dst,
        const int* __restrict__ row_start, const int* __restrict__ csr_eid,
        const unsigned* __restrict__ pkh, const int* __restrict__ ei,
        const float* __restrict__ bias, const float* __restrict__ ln_g,
        const float* __restrict__ ln_b, float* __restrict__ out) {
    int t = threadIdx.x;
    int wave = t >> 6, lane = t & 63;
    int n = blockIdx.x * 4 + wave;
    if (n >= NN) return;

    int start = row_start[n];
    int deg   = row_start[n + 1] - start;
    int head  = lane >> 4;

    float accx = 0.f, accy = 0.f, s_own = 0.f, aes_own = 0.f;
    const int* ep = csr_eid + start;

    int k = 0;
    for (; k + 8 <= deg; k += 8) {
        int ev[8];
        #pragma unroll
        for (int j = 0; j < 8; ++j) ev[j] = ep[k + j];
        unsigned pv[8]; int sv[8];
        #pragma unroll
        for (int j = 0; j < 8; ++j) {
            pv[j] = pkh[(size_t)ev[j] * 4 + head];
            sv[j] = ei[ev[j]];
        }
        __half2 hv[8];
        #pragma unroll
        for (int j = 0; j < 8; ++j) hv[j] = hb[(long)sv[j] * 64 + lane];
        #pragma unroll
        for (int j = 0; j < 8; ++j) {
            float2 wf = __half22float2(*(__half2*)&pv[j]);
            s_own += wf.x;
            aes_own += wf.y;
            float2 hf = __half22float2(hv[j]);
            accx = fmaf(wf.x, hf.x, accx);
            accy = fmaf(wf.x, hf.y, accy);
        }
    }
    for (; k < deg; ++k) {
        int e = ep[k];
        unsigned p = pkh[(size_t)e * 4 + head];
        int src = ei[e];
        __half2 hv = hb[(long)src * 64 + lane];
        float2 wf = __half22float2(*(__half2*)&p);
        s_own += wf.x;
        aes_own += wf.y;
        float2 hf = __half22float2(hv);
        accx = fmaf(wf.x, hf.x, accx);
        accy = fmaf(wf.x, hf.y, accy);
    }

    float inv_deg = 1.0f / fmaxf((float)deg, 1.0f);
    float v = a_src[n * 4 + head] + a_dst[n * 4 + head] + aes_own * inv_deg;
    v = (v >= 0.f) ? v : NEGS * v;
    float w0 = __expf(v);
    s_own += w0;
    float2 hn = __half22float2(hb[(long)n * 64 + lane]);
    accx = fmaf(w0, hn.x, accx);
    accy = fmaf(w0, hn.y, accy);
    float is = 1.0f / s_own;
    accx *= is; accy *= is;

    int c0 = lane * 2;
    float2 b2 = *(const float2*)&bias[c0];
    float2 x2 = *(const float2*)&x[(long)n * DINN + c0];
    float oa = accx + b2.x + x2.x;
    float ob = accy + b2.y + x2.y;
    float sum = oa + ob, sumsq = oa * oa + ob * ob;
    #pragma unroll
    for (int d2 = 1; d2 < 64; d2 <<= 1) {
        sum   += __shfl_xor(sum, d2);
        sumsq += __shfl_xor(sumsq, d2);
    }
    float mu  = sum * (1.0f / DINN);
    float var = sumsq * (1.0f / DINN) - mu * mu;
    float rs  = rsqrtf(var + LNEPS);
    float2 g2  = *(const float2*)&ln_g[c0];
    float2 lb2 = *(const float2*)&ln_b[c0];
    float2 o2;
    o2.x = (oa - mu) * rs * g2.x + lb2.x;
    o2.y = (ob - mu) * rs * g2.y + lb2.y;
    *(float2*)&out[(long)n * DINN + c0] = o2;
}

// ---------------------------------------------------------------------------
extern "C" void kernel_launch(void* const* d_in, const int* in_sizes, int n_in,
                              void* d_out, int out_size, void* d_ws, size_t ws_size,
                              hipStream_t stream) {
    const float* x         = (const float*)d_in[0];
    const int*   ei        = (const int*)d_in[1];
    const float* edge_attr = (const float*)d_in[2];
    const float* W_ep      = (const float*)d_in[3];
    const float* b_ep      = (const float*)d_in[4];
    const float* W_lin     = (const float*)d_in[5];
    const float* W_edge    = (const float*)d_in[6];
    const float* att_src   = (const float*)d_in[7];
    const float* att_dst   = (const float*)d_in[8];
    const float* att_edge  = (const float*)d_in[9];
    const float* bias      = (const float*)d_in[10];
    const float* ln_g      = (const float*)d_in[11];
    const float* ln_b      = (const float*)d_in[12];
    float* out = (float*)d_out;

    char* ws = (char*)d_ws;
    size_t o = 0;
    auto take = [&](size_t bytes) -> char* {
        char* p = ws + o;
        o = (o + bytes + 255) & ~(size_t)255;
        return p;
    };
    __half* hbuf      = (__half*)take((size_t)NN * DINN * 2);   // 12.8 MB
    float*  a_src     = (float*)take((size_t)NN * 4 * 4);
    float*  a_dst     = (float*)take((size_t)NN * 4 * 4);
    int*    cnt       = (int*)  take((size_t)NN * CPAD * 4);    // 6.4 MB, zeroed
    int*    row_start = (int*)  take((size_t)(NN + 1) * 4);
    int*    rank      = (int*)  take((size_t)EE * 4);           // 3.2 MB
    int*    partial   = (int*)  take((size_t)SCAN_NB * 4);
    int*    poff      = (int*)  take((size_t)SCAN_NB * 4);
    uint4*  payload   = (uint4*)take((size_t)EE * 16);          // 12.8 MB
    int*    csr_eid   = (int*)  take((size_t)EE * 4);           // 3.2 MB

    hipMemsetAsync(cnt, 0, (size_t)NN * CPAD * 4, stream);

    k_node<<<(NN + 63) / 64, 256, 0, stream>>>(x, W_lin, att_src, att_dst,
                                               hbuf, a_src, a_dst);
    k_edgeA<<<(EE + 511) / 512, 256, 0, stream>>>(ei, edge_attr, W_ep, b_ep,
                                                  W_edge, att_edge, a_src, a_dst,
                                                  cnt, rank, payload);
    k_scanA<<<SCAN_NB, 256, 0, stream>>>(cnt, partial);
    k_scanB<<<1, 256, 0, stream>>>(partial, poff, row_start);
    k_scanC<<<SCAN_NB, 256, 0, stream>>>(cnt, poff, row_start);
    k_edgeB<<<(EE / 4 + 255) / 256, 256, 0, stream>>>(ei, rank, row_start, csr_eid);
    k_aggregate<<<(NN + 3) / 4, 256, 0, stream>>>(x, (const __half2*)hbuf,
                                                  a_src, a_dst, row_start, csr_eid,
                                                  (const unsigned*)payload, ei,
                                                  bias, ln_g, ln_b, out);
}

// Round 9
// 283.257 us; speedup vs baseline: 1.0377x; 1.0377x over previous
//
#include <hip/hip_runtime.h>
#include <hip/hip_fp16.h>
#include <math.h>

#define NN   50000
#define EE   800000
#define HH   4
#define CC   32
#define DINN 128
#define ED   16
#define NEGS 0.2f
#define LNEPS 1e-5f
#define SCAN_NB ((NN + 255) / 256)   // 196
#define CPAD 32                      // cnt stride: 1 counter per 128B line

struct __align__(16) Hp4 { __half2 a, b, c, d; };

// ---------------------------------------------------------------------------
// K2: h = x @ W_lin (N x 128) -> hbuf fp16, plus a_src/a_dst.
// ---------------------------------------------------------------------------
__global__ __launch_bounds__(256, 3) void k_node(
        const float* __restrict__ x, const float* __restrict__ W_lin,
        const float* __restrict__ att_src, const float* __restrict__ att_dst,
        __half* __restrict__ hb, float* __restrict__ a_src, float* __restrict__ a_dst) {
    __shared__ float xr[64 * 132];      // 33.8 KB
    int t = threadIdx.x;
    int row0 = blockIdx.x * 64;

    #pragma unroll
    for (int i = 0; i < 8; ++i) {
        int idx = t + 256 * i;          // 0..2047
        int r = idx >> 5, kq = idx & 31;
        int row = row0 + r;
        float4 v = make_float4(0.f, 0.f, 0.f, 0.f);
        if (row < NN) v = ((const float4*)x)[(long)row * 32 + kq];
        *(float4*)&xr[r * 132 + kq * 4] = v;
    }
    __syncthreads();

    int colg = t & 15, rowg = t >> 4;
    int c0 = colg * 8;
    const float* Wp = W_lin + c0;
    float acc[4][8] = {};

    #pragma unroll 2
    for (int k = 0; k < DINN; k += 2) {
        float4 wa0 = *(const float4*)&Wp[(long)k * DINN];
        float4 wb0 = *(const float4*)&Wp[(long)k * DINN + 4];
        float4 wa1 = *(const float4*)&Wp[(long)(k + 1) * DINN];
        float4 wb1 = *(const float4*)&Wp[(long)(k + 1) * DINN + 4];
        #pragma unroll
        for (int i = 0; i < 4; ++i) {
            float2 xv = *(const float2*)&xr[(rowg * 4 + i) * 132 + k];
            acc[i][0] = fmaf(xv.x, wa0.x, acc[i][0]);
            acc[i][1] = fmaf(xv.x, wa0.y, acc[i][1]);
            acc[i][2] = fmaf(xv.x, wa0.z, acc[i][2]);
            acc[i][3] = fmaf(xv.x, wa0.w, acc[i][3]);
            acc[i][4] = fmaf(xv.x, wb0.x, acc[i][4]);
            acc[i][5] = fmaf(xv.x, wb0.y, acc[i][5]);
            acc[i][6] = fmaf(xv.x, wb0.z, acc[i][6]);
            acc[i][7] = fmaf(xv.x, wb0.w, acc[i][7]);
            acc[i][0] = fmaf(xv.y, wa1.x, acc[i][0]);
            acc[i][1] = fmaf(xv.y, wa1.y, acc[i][1]);
            acc[i][2] = fmaf(xv.y, wa1.z, acc[i][2]);
            acc[i][3] = fmaf(xv.y, wa1.w, acc[i][3]);
            acc[i][4] = fmaf(xv.y, wb1.x, acc[i][4]);
            acc[i][5] = fmaf(xv.y, wb1.y, acc[i][5]);
            acc[i][6] = fmaf(xv.y, wb1.z, acc[i][6]);
            acc[i][7] = fmaf(xv.y, wb1.w, acc[i][7]);
        }
    }

    int head = colg >> 2;
    int cw = c0 & 31;
    float4 as0 = *(const float4*)&att_src[head * CC + cw];
    float4 as1 = *(const float4*)&att_src[head * CC + cw + 4];
    float4 ad0 = *(const float4*)&att_dst[head * CC + cw];
    float4 ad1 = *(const float4*)&att_dst[head * CC + cw + 4];
    #pragma unroll
    for (int i = 0; i < 4; ++i) {
        int row = row0 + rowg * 4 + i;
        if (row < NN) {
            Hp4 p;
            p.a = __floats2half2_rn(acc[i][0], acc[i][1]);
            p.b = __floats2half2_rn(acc[i][2], acc[i][3]);
            p.c = __floats2half2_rn(acc[i][4], acc[i][5]);
            p.d = __floats2half2_rn(acc[i][6], acc[i][7]);
            *(Hp4*)&hb[(long)row * DINN + c0] = p;
        }
        float ps = acc[i][0]*as0.x + acc[i][1]*as0.y + acc[i][2]*as0.z + acc[i][3]*as0.w
                 + acc[i][4]*as1.x + acc[i][5]*as1.y + acc[i][6]*as1.z + acc[i][7]*as1.w;
        float pd = acc[i][0]*ad0.x + acc[i][1]*ad0.y + acc[i][2]*ad0.z + acc[i][3]*ad0.w
                 + acc[i][4]*ad1.x + acc[i][5]*ad1.y + acc[i][6]*ad1.z + acc[i][7]*ad1.w;
        ps += __shfl_xor(ps, 1); ps += __shfl_xor(ps, 2);
        pd += __shfl_xor(pd, 1); pd += __shfl_xor(pd, 2);
        if ((colg & 3) == 0 && row < NN) {
            a_src[row * 4 + head] = ps;
            a_dst[row * 4 + head] = pd;
        }
    }
}

// ---------------------------------------------------------------------------
// K3 (edgeA): 2 edges/thread. Per edge: ea GEMM, a_e, alpha logits,
// payload[e] = {half2(exp(alpha_h), a_e_h)}x4 (coalesced, edge order),
// rank[e] = atomicAdd(cnt + dst*CPAD, 1)  (one counter per 128B line,
// atomic issued before the GEMM so its latency hides under compute).
// ---------------------------------------------------------------------------
__global__ __launch_bounds__(256) void k_edgeA(
        const int* __restrict__ ei, const float* __restrict__ edge_attr,
        const float* __restrict__ W_ep, const float* __restrict__ b_ep,
        const float* __restrict__ W_edge, const float* __restrict__ att_edge,
        const float* __restrict__ a_src, const float* __restrict__ a_dst,
        int* __restrict__ cnt, int* __restrict__ rank,
        uint4* __restrict__ payload) {
    __shared__ float Wl[ED * ED];
    __shared__ float bl[ED];
    __shared__ float vl[ED * 4];
    int t = threadIdx.x;
    if (t < ED * ED) Wl[t] = W_ep[t];
    if (t < ED) bl[t] = b_ep[t];
    if (t >= 192 && t < 192 + 64) {      // 64 threads build v_edge
        int q = t - 192;
        int d = q >> 2, h = q & 3;
        float s = 0.f;
        #pragma unroll 8
        for (int c = 0; c < CC; ++c)
            s += W_edge[d * (HH * CC) + h * CC + c] * att_edge[h * CC + c];
        vl[q] = s;
    }
    __syncthreads();

    int e0 = blockIdx.x * 512 + t;       // edges e0 and e0+256

    #pragma unroll
    for (int u = 0; u < 2; ++u) {
        int e = e0 + u * 256;
        if (e >= EE) break;

        int src = ei[e];
        int dst = ei[EE + e];

        float a[ED];
        const float4* ap = (const float4*)(edge_attr + (long)e * ED);
        float4 a0 = ap[0], a1 = ap[1], a2 = ap[2], a3 = ap[3];
        a[0]=a0.x; a[1]=a0.y; a[2]=a0.z; a[3]=a0.w;
        a[4]=a1.x; a[5]=a1.y; a[6]=a1.z; a[7]=a1.w;
        a[8]=a2.x; a[9]=a2.y; a[10]=a2.z; a[11]=a2.w;
        a[12]=a3.x; a[13]=a3.y; a[14]=a3.z; a[15]=a3.w;

        float4 s4 = *(const float4*)&a_src[src * 4];
        float4 d4 = *(const float4*)&a_dst[dst * 4];

        int rk = atomicAdd(cnt + (long)dst * CPAD, 1);

        float r[ED];
        #pragma unroll
        for (int j = 0; j < ED; ++j) r[j] = bl[j];
        #pragma unroll
        for (int d = 0; d < ED; ++d) {
            float av = a[d];
            #pragma unroll
            for (int j = 0; j < ED; ++j) r[j] = fmaf(av, Wl[d * ED + j], r[j]);
        }

        float ae0 = 0.f, ae1 = 0.f, ae2 = 0.f, ae3 = 0.f;
        #pragma unroll
        for (int d = 0; d < ED; ++d) {
            float rd = fmaxf(r[d], 0.f);
            ae0 = fmaf(rd, vl[d * 4 + 0], ae0);
            ae1 = fmaf(rd, vl[d * 4 + 1], ae1);
            ae2 = fmaf(rd, vl[d * 4 + 2], ae2);
            ae3 = fmaf(rd, vl[d * 4 + 3], ae3);
        }

        float v0 = s4.x + d4.x + ae0;
        float v1 = s4.y + d4.y + ae1;
        float v2 = s4.z + d4.z + ae2;
        float v3 = s4.w + d4.w + ae3;
        v0 = (v0 >= 0.f) ? v0 : NEGS * v0;
        v1 = (v1 >= 0.f) ? v1 : NEGS * v1;
        v2 = (v2 >= 0.f) ? v2 : NEGS * v2;
        v3 = (v3 >= 0.f) ? v3 : NEGS * v3;

        __half2 p0 = __floats2half2_rn(__expf(v0), ae0);
        __half2 p1 = __floats2half2_rn(__expf(v1), ae1);
        __half2 p2 = __floats2half2_rn(__expf(v2), ae2);
        __half2 p3 = __floats2half2_rn(__expf(v3), ae3);
        payload[e] = make_uint4(*(unsigned*)&p0, *(unsigned*)&p1,
                                *(unsigned*)&p2, *(unsigned*)&p3);
        rank[e] = rk;
    }
}

// ---------------------------------------------------------------------------
// K4a/b/c: hierarchical exclusive scan of cnt (stride CPAD) -> row_start
// ---------------------------------------------------------------------------
__global__ __launch_bounds__(256) void k_scanA(const int* __restrict__ cnt,
                                               int* __restrict__ partial) {
    int t = threadIdx.x, b = blockIdx.x;
    int i = b * 256 + t;
    int v = (i < NN) ? cnt[(long)i * CPAD] : 0;
    #pragma unroll
    for (int d = 1; d < 64; d <<= 1) v += __shfl_xor(v, d);
    __shared__ int wt[4];
    if ((t & 63) == 0) wt[t >> 6] = v;
    __syncthreads();
    if (t == 0) partial[b] = wt[0] + wt[1] + wt[2] + wt[3];
}

__global__ __launch_bounds__(256) void k_scanB(const int* __restrict__ partial,
                                               int* __restrict__ poff,
                                               int* __restrict__ row_start) {
    int t = threadIdx.x;
    int lane = t & 63, w = t >> 6;
    int v = (t < SCAN_NB) ? partial[t] : 0;
    int sv = v;
    #pragma unroll
    for (int d = 1; d < 64; d <<= 1) {
        int o = __shfl_up(sv, d);
        if (lane >= d) sv += o;
    }
    __shared__ int wt[4];
    if (lane == 63) wt[w] = sv;
    __syncthreads();
    int base = 0;
    for (int j = 0; j < w; ++j) base += wt[j];
    if (t < SCAN_NB) poff[t] = base + sv - v;
    if (t == 255) row_start[NN] = wt[0] + wt[1] + wt[2] + wt[3];
}

__global__ __launch_bounds__(256) void k_scanC(const int* __restrict__ cnt,
                                               const int* __restrict__ poff,
                                               int* __restrict__ row_start) {
    int t = threadIdx.x, b = blockIdx.x;
    int i = b * 256 + t;
    int v = (i < NN) ? cnt[(long)i * CPAD] : 0;
    int lane = t & 63, w = t >> 6;
    int sv = v;
    #pragma unroll
    for (int d = 1; d < 64; d <<= 1) {
        int o = __shfl_up(sv, d);
        if (lane >= d) sv += o;
    }
    __shared__ int wt[4];
    if (lane == 63) wt[w] = sv;
    __syncthreads();
    int base = 0;
    for (int j = 0; j < w; ++j) base += wt[j];
    if (i < NN) row_start[i] = poff[b] + base + sv - v;
}

// ---------------------------------------------------------------------------
// K5 (edgeB): permute payload+src into CSR order (coalesced reads, scattered
// 20B writes). 4 edges/thread for deep batching.
// ---------------------------------------------------------------------------
__global__ __launch_bounds__(256) void k_edgeB(
        const int* __restrict__ ei, const uint4* __restrict__ payload,
        const int* __restrict__ rank, const int* __restrict__ row_start,
        uint4* __restrict__ pk, int* __restrict__ csr_src) {
    int base = (blockIdx.x * 256 + threadIdx.x) * 4;
    if (base + 3 < EE) {
        int4 s4 = *(const int4*)(ei + base);
        int4 d4 = *(const int4*)(ei + EE + base);
        int4 r4 = *(const int4*)(rank + base);
        uint4 p0 = payload[base], p1 = payload[base + 1];
        uint4 p2 = payload[base + 2], p3 = payload[base + 3];
        int q0 = row_start[d4.x] + r4.x;
        int q1 = row_start[d4.y] + r4.y;
        int q2 = row_start[d4.z] + r4.z;
        int q3 = row_start[d4.w] + r4.w;
        pk[q0] = p0; pk[q1] = p1; pk[q2] = p2; pk[q3] = p3;
        csr_src[q0] = s4.x; csr_src[q1] = s4.y;
        csr_src[q2] = s4.z; csr_src[q3] = s4.w;
    } else {
        for (int e = base; e < EE; ++e) {
            int q = row_start[ei[EE + e]] + rank[e];
            pk[q] = payload[e];
            csr_src[q] = ei[e];
        }
    }
}

// ---------------------------------------------------------------------------
// K6: one wave per node, single pass, 8-wide unrolled, coalesced CSR reads.
// Lane owns channels {2*lane, 2*lane+1}; head = lane>>4.
// ---------------------------------------------------------------------------
__global__ __launch_bounds__(256) void k_aggregate(
        const float* __restrict__ x, const __half2* __restrict__ hb,
        const float* __restrict__ a_src, const float* __restrict__ a_dst,
        const int* __restrict__ row_start,
        const unsigned* __restrict__ pkh, const int* __restrict__ srcs,
        const float* __restrict__ bias, const float* __restrict__ ln_g,
        const float* __restrict__ ln_b, float* __restrict__ out) {
    int t = threadIdx.x;
    int wave = t >> 6, lane = t & 63;
    int n = blockIdx.x * 4 + wave;
    if (n >= NN) return;

    int start = row_start[n];
    int deg   = row_start[n + 1] - start;
    int head  = lane >> 4;

    float accx = 0.f, accy = 0.f, s_own = 0.f, aes_own = 0.f;
    const unsigned* pp = pkh + (size_t)start * 4 + head;
    const int* sp = srcs + start;

    int k = 0;
    for (; k + 8 <= deg; k += 8) {
        unsigned pv[8]; int sv[8];
        #pragma unroll
        for (int j = 0; j < 8; ++j) {
            pv[j] = pp[(size_t)(k + j) * 4];
            sv[j] = sp[k + j];
        }
        __half2 hv[8];
        #pragma unroll
        for (int j = 0; j < 8; ++j) hv[j] = hb[(long)sv[j] * 64 + lane];
        #pragma unroll
        for (int j = 0; j < 8; ++j) {
            float2 wf = __half22float2(*(__half2*)&pv[j]);
            s_own += wf.x;
            aes_own += wf.y;
            float2 hf = __half22float2(hv[j]);
            accx = fmaf(wf.x, hf.x, accx);
            accy = fmaf(wf.x, hf.y, accy);
        }
    }
    for (; k < deg; ++k) {
        unsigned p = pp[(size_t)k * 4];
        int src = sp[k];
        __half2 hv = hb[(long)src * 64 + lane];
        float2 wf = __half22float2(*(__half2*)&p);
        s_own += wf.x;
        aes_own += wf.y;
        float2 hf = __half22float2(hv);
        accx = fmaf(wf.x, hf.x, accx);
        accy = fmaf(wf.x, hf.y, accy);
    }

    float inv_deg = 1.0f / fmaxf((float)deg, 1.0f);
    float v = a_src[n * 4 + head] + a_dst[n * 4 + head] + aes_own * inv_deg;
    v = (v >= 0.f) ? v : NEGS * v;
    float w0 = __expf(v);
    s_own += w0;
    float2 hn = __half22float2(hb[(long)n * 64 + lane]);
    accx = fmaf(w0, hn.x, accx);
    accy = fmaf(w0, hn.y, accy);
    float is = 1.0f / s_own;
    accx *= is; accy *= is;

    int c0 = lane * 2;
    float2 b2 = *(const float2*)&bias[c0];
    float2 x2 = *(const float2*)&x[(long)n * DINN + c0];
    float oa = accx + b2.x + x2.x;
    float ob = accy + b2.y + x2.y;
    float sum = oa + ob, sumsq = oa * oa + ob * ob;
    #pragma unroll
    for (int d2 = 1; d2 < 64; d2 <<= 1) {
        sum   += __shfl_xor(sum, d2);
        sumsq += __shfl_xor(sumsq, d2);
    }
    float mu  = sum * (1.0f / DINN);
    float var = sumsq * (1.0f / DINN) - mu * mu;
    float rs  = rsqrtf(var + LNEPS);
    float2 g2  = *(const float2*)&ln_g[c0];
    float2 lb2 = *(const float2*)&ln_b[c0];
    float2 o2;
    o2.x = (oa - mu) * rs * g2.x + lb2.x;
    o2.y = (ob - mu) * rs * g2.y + lb2.y;
    *(float2*)&out[(long)n * DINN + c0] = o2;
}

// ---------------------------------------------------------------------------
extern "C" void kernel_launch(void* const* d_in, const int* in_sizes, int n_in,
                              void* d_out, int out_size, void* d_ws, size_t ws_size,
                              hipStream_t stream) {
    const float* x         = (const float*)d_in[0];
    const int*   ei        = (const int*)d_in[1];
    const float* edge_attr = (const float*)d_in[2];
    const float* W_ep      = (const float*)d_in[3];
    const float* b_ep      = (const float*)d_in[4];
    const float* W_lin     = (const float*)d_in[5];
    const float* W_edge    = (const float*)d_in[6];
    const float* att_src   = (const float*)d_in[7];
    const float* att_dst   = (const float*)d_in[8];
    const float* att_edge  = (const float*)d_in[9];
    const float* bias      = (const float*)d_in[10];
    const float* ln_g      = (const float*)d_in[11];
    const float* ln_b      = (const float*)d_in[12];
    float* out = (float*)d_out;

    char* ws = (char*)d_ws;
    size_t o = 0;
    auto take = [&](size_t bytes) -> char* {
        char* p = ws + o;
        o = (o + bytes + 255) & ~(size_t)255;
        return p;
    };
    __half* hbuf      = (__half*)take((size_t)NN * DINN * 2);   // 12.8 MB
    float*  a_src     = (float*)take((size_t)NN * 4 * 4);
    float*  a_dst     = (float*)take((size_t)NN * 4 * 4);
    int*    cnt       = (int*)  take((size_t)NN * CPAD * 4);    // 6.4 MB, zeroed
    int*    row_start = (int*)  take((size_t)(NN + 1) * 4);
    int*    rank      = (int*)  take((size_t)EE * 4);           // 3.2 MB
    int*    partial   = (int*)  take((size_t)SCAN_NB * 4);
    int*    poff      = (int*)  take((size_t)SCAN_NB * 4);
    uint4*  payload   = (uint4*)take((size_t)EE * 16);          // 12.8 MB
    uint4*  pk        = (uint4*)take((size_t)EE * 16);          // 12.8 MB
    int*    csr_src   = (int*)  take((size_t)EE * 4);           // 3.2 MB

    hipMemsetAsync(cnt, 0, (size_t)NN * CPAD * 4, stream);

    k_node<<<(NN + 63) / 64, 256, 0, stream>>>(x, W_lin, att_src, att_dst,
                                               hbuf, a_src, a_dst);
    k_edgeA<<<(EE + 511) / 512, 256, 0, stream>>>(ei, edge_attr, W_ep, b_ep,
                                                  W_edge, att_edge, a_src, a_dst,
                                                  cnt, rank, payload);
    k_scanA<<<SCAN_NB, 256, 0, stream>>>(cnt, partial);
    k_scanB<<<1, 256, 0, stream>>>(partial, poff, row_start);
    k_scanC<<<SCAN_NB, 256, 0, stream>>>(cnt, poff, row_start);
    k_edgeB<<<(EE / 4 + 255) / 256, 256, 0, stream>>>(ei, payload, rank,
                                                      row_start, pk, csr_src);
    k_aggregate<<<(NN + 3) / 4, 256, 0, stream>>>(x, (const __half2*)hbuf,
                                                  a_src, a_dst, row_start,
                                                  (const unsigned*)pk, csr_src,
                                                  bias, ln_g, ln_b, out);
}